// Round 5
// baseline (548.552 us; speedup 1.0000x reference)
//
#include <hip/hip_runtime.h>
#include <stdint.h>

typedef __bf16 bf16_t;
typedef bf16_t bf16x8 __attribute__((ext_vector_type(8)));
typedef float f32x4 __attribute__((ext_vector_type(4)));
typedef unsigned int u32;
typedef unsigned short u16;

#define DEV_INLINE __device__ __forceinline__

// ---------- constants ----------
#define S_LEN 2048
#define D_MODEL 4096
#define HQ 32
#define HK 8
#define HD 128
#define NQKV 6144   // HQ*HD + 2*HK*HD

DEV_INLINE u16 f2bf(float x) {
  union { float f; uint32_t u; } v; v.f = x;
  uint32_t r = v.u + 0x7FFFu + ((v.u >> 16) & 1u);  // RNE
  return (u16)(r >> 16);
}
DEV_INLINE float bf2f(u16 x) {
  union { uint32_t u; float f; } v; v.u = ((uint32_t)x) << 16;
  return v.f;
}
DEV_INLINE u32 pack2bf(float a, float b) {
  return (u32)f2bf(a) | ((u32)f2bf(b) << 16);
}

DEV_INLINE void async_load16(const void* g, void* l) {
  __builtin_amdgcn_global_load_lds(
      (const __attribute__((address_space(1))) u32*)g,
      (__attribute__((address_space(3))) u32*)l, 16, 0, 0);
}

DEV_INLINE f32x4 mfma16(bf16x8 a, bf16x8 b, f32x4 c) {
  return __builtin_amdgcn_mfma_f32_16x16x32_bf16(a, b, c, 0, 0, 0);
}

// ---------- elementwise f32 -> bf16 ----------
__global__ void cvt_f32_bf16(const float* __restrict__ in, u16* __restrict__ out, int n) {
  int i = (blockIdx.x * blockDim.x + threadIdx.x) * 4;
  if (i >= n) return;
  float4 v = *(const float4*)(in + i);
  union { u16 s[4]; uint2 u; } o;
  o.s[0] = f2bf(v.x); o.s[1] = f2bf(v.y); o.s[2] = f2bf(v.z); o.s[3] = f2bf(v.w);
  *(uint2*)(out + i) = o.u;
}

// ---------- transpose fp32 (R,C) -> bf16 (C,R) ----------
__global__ void transpose_f32_bf16(const float* __restrict__ in, u16* __restrict__ out,
                                   int R, int C) {
  __shared__ float tile[32][33];
  int tx = threadIdx.x, ty = threadIdx.y;           // block (32,8)
  int c0 = blockIdx.x * 32, r0 = blockIdx.y * 32;
#pragma unroll
  for (int i = 0; i < 4; ++i)
    tile[ty + i * 8][tx] = in[(long)(r0 + ty + i * 8) * C + c0 + tx];
  __syncthreads();
#pragma unroll
  for (int i = 0; i < 4; ++i)
    out[(long)(c0 + ty + i * 8) * R + r0 + tx] = f2bf(tile[tx][ty + i * 8]);
}

// ---------- transpose bf16 (R, ld_in cols, slice [col_off, col_off+C)) -> (C, R) ----------
__global__ void transpose_bf16(const u16* __restrict__ in, u16* __restrict__ out,
                               int R, int C, int ld_in, int col_off) {
  __shared__ u16 tile[32][33];
  int tx = threadIdx.x, ty = threadIdx.y;           // block (32,8)
  int c0 = blockIdx.x * 32, r0 = blockIdx.y * 32;
#pragma unroll
  for (int i = 0; i < 4; ++i)
    tile[ty + i * 8][tx] = in[(long)(r0 + ty + i * 8) * ld_in + col_off + c0 + tx];
  __syncthreads();
#pragma unroll
  for (int i = 0; i < 4; ++i)
    out[(long)(c0 + ty + i * 8) * R + r0 + tx] = tile[tx][ty + i * 8];
}

// ---------- RoPE on bf16 (strided input slice) -> packed bf16 ----------
__global__ void rope_bf16(const u16* __restrict__ in, const float* __restrict__ cosb,
                          const float* __restrict__ sinb, u16* __restrict__ out,
                          int H, int ld_in, int col_off, float scale) {
  int idx = blockIdx.x * blockDim.x + threadIdx.x;   // over S*H*64
  int j = idx & 63;
  int sh = idx >> 6;            // s*H + h
  int s = sh / H, h = sh - s * H;
  const u16* ip = in + (long)s * ld_in + col_off + h * HD;
  union { u32 u; u16 s2[2]; } v; v.u = *(const u32*)(ip + 2 * j);
  float q0 = bf2f(v.s2[0]), q1 = bf2f(v.s2[1]);
  float c = cosb[s * 64 + j], sn = sinb[s * 64 + j];
  union { u16 s2[2]; u32 u; } o;
  o.s2[0] = f2bf((q0 * c - q1 * sn) * scale);
  o.s2[1] = f2bf((q0 * sn + q1 * c) * scale);
  *(u32*)(out + (long)sh * HD + 2 * j) = o.u;
}

#define BARRIER() asm volatile("s_barrier" ::: "memory")
#define WAIT_VM(N) asm volatile("s_waitcnt vmcnt(" #N ")" ::: "memory")

// ---------- GEMM v3: B-direct-to-register, A LDS ring, 2 blocks/CU ----------
// C(M,N) = A(M,K)bf16 @ Bt(N,K)^T.  BM=128, 256 thr (4 waves, 1M x 4N),
// wave tile 128 x (BN/4).  A: 4-slot LDS ring (8KB/slot, 32KB total).
// B: weights loaded straight from global (L2/L3-resident) into VGPRs,
// double-buffered one K-tile ahead -> no B LDS writes, no B ds_reads.
// Grid 512 blocks -> 2 blocks/CU: two independent barrier domains per CU so
// one block's ds_read/stage phase overlaps the other's MFMA phase (the r4
// counter evidence showed a single phase-locked block serializes LDS+MFMA).
// Ring safety (no manual vmcnt in loop):
//  RAW A(t): A(t) staged in iter t-3; B(t-1) loaded in iter t-2 (strictly
//    later: loads/DMA cannot cross the "memory"-clobber barriers); compiler
//    waits on B(t-1) before tile t-1's MFMAs; per-wave in-order vmcnt
//    retirement => A(t) is in LDS before tile t-1's MFMAs complete; the
//    end-of-(t-1) barrier then publishes it to all waves before tile t reads.
//  WAR slot (t+3)&3 == (t-1)&3: all waves' tile t-1 ds_reads are consumed by
//    MFMAs (lgkm) before the end-of-(t-1) barrier; stage(t+3) issues after.
//  Prologue: one WAIT_VM(0) covers tiles 0..2 + B(0).
template <int BN, bool BF16OUT>
__global__ __launch_bounds__(256, 2) void gemm_bdir(
    const u16* __restrict__ A, const u16* __restrict__ Bt, void* __restrict__ Cv,
    int N, int K) {
  constexpr int NF = BN / 64;           // n-frags per wave
  __shared__ __attribute__((aligned(16))) u16 lds[4][128 * 32];

  const int tid = threadIdx.x;
  const int lane = tid & 63, wave = tid >> 6;
  const int quad = lane >> 4, l15 = lane & 15;

  // T1: XCD-chunked swizzle (grid 512 = 8 XCDs x 64)
  const int gx = gridDim.x;
  const int bid = blockIdx.y * gx + blockIdx.x;
  const int cpx = (gx * gridDim.y) >> 3;
  const int sw = (bid & 7) * cpx + (bid >> 3);
  const int bn = sw % gx, bm = sw / gx;

  const long arow = (long)bm * 128, brow = (long)bn * BN;
  const int NT = K >> 5;

  // per-thread A staging pointers (2 x 16B chunks), chunk swizzle cc^((row>>1)&3)
  const u16* asrc[2];
  int adst[2];
#pragma unroll
  for (int j = 0; j < 2; ++j) {
    int c = tid + j * 256;
    int row = c >> 2, cc = c & 3, cs = cc ^ ((row >> 1) & 3);
    asrc[j] = A + (arow + row) * (long)K + cs * 8;
    adst[j] = c * 8;
  }
  // per-frag B pointers (row-gather: 4 lanes/quad share one 64B line)
  const u16* bptr[NF];
#pragma unroll
  for (int j = 0; j < NF; ++j)
    bptr[j] = Bt + (brow + wave * (NF * 16) + j * 16 + l15) * (long)K + quad * 8;

  auto stageA = [&](int ts) {
    const int k0 = ts * 32;
    u16* base = &lds[ts & 3][0];
#pragma unroll
    for (int j = 0; j < 2; ++j) async_load16(asrc[j] + k0, base + adst[j]);
  };

  f32x4 acc[8][NF] = {};
  bf16x8 b0[NF], b1[NF];

  // prologue: A tiles 0..2 staged, B(0) in regs, drain once
  stageA(0); stageA(1); stageA(2);
#pragma unroll
  for (int j = 0; j < NF; ++j) b0[j] = *(const bf16x8*)(bptr[j]);
  WAIT_VM(0);
  BARRIER();

#define GD_TILE(T, BR, BPRE)                                             \
  {                                                                      \
    if ((T) + 3 < NT) stageA((T) + 3);                                   \
    if ((T) + 1 < NT) {                                                  \
      _Pragma("unroll")                                                  \
      for (int j = 0; j < NF; ++j)                                       \
        BPRE[j] = *(const bf16x8*)(bptr[j] + ((T) + 1) * 32);            \
    }                                                                    \
    const u16* lbase = &lds[(T) & 3][0];                                 \
    __builtin_amdgcn_s_setprio(1);                                       \
    _Pragma("unroll")                                                    \
    for (int i = 0; i < 8; ++i) {                                        \
      int row = i * 16 + l15;                                            \
      bf16x8 af = *(const bf16x8*)(lbase + row * 32 +                    \
                                   ((quad ^ ((row >> 1) & 3)) * 8));     \
      _Pragma("unroll")                                                  \
      for (int j = 0; j < NF; ++j)                                       \
        acc[i][j] = mfma16(af, BR[j], acc[i][j]);                        \
    }                                                                    \
    __builtin_amdgcn_s_setprio(0);                                       \
    BARRIER();                                                           \
  }

  for (int t = 0; t < NT; t += 2) {   // NT even (K multiple of 64)
    GD_TILE(t, b0, b1);
    GD_TILE(t + 1, b1, b0);
  }
#undef GD_TILE

  // epilogue: C row from A (quad*4+r), col from B (l15)
#pragma unroll
  for (int i = 0; i < 8; ++i) {
    const long row = (long)bm * 128 + i * 16 + quad * 4;
#pragma unroll
    for (int j = 0; j < NF; ++j) {
      const int col = bn * BN + wave * (NF * 16) + j * 16 + l15;
      if constexpr (BF16OUT) {
        u16* C = (u16*)Cv;
#pragma unroll
        for (int r = 0; r < 4; ++r) C[(row + r) * N + col] = f2bf(acc[i][j][r]);
      } else {
        float* C = (float*)Cv;
#pragma unroll
        for (int r = 0; r < 4; ++r) C[(row + r) * N + col] = acc[i][j][r];
      }
    }
  }
}

// ---------- flash attention v2 (unchanged from r4) ----------
#define NEG_INF -1e30f
__global__ __launch_bounds__(256, 2) void attn_fwd(
    const u16* __restrict__ Qb, const u16* __restrict__ Kb,
    const u16* __restrict__ Vt, u16* __restrict__ Ob) {
  __shared__ __attribute__((aligned(16))) u16 Ks[2][64 * 128];   // kpos-major
  __shared__ __attribute__((aligned(16))) u16 Vs[2][128 * 64];   // d-major (V^T)
  __shared__ __attribute__((aligned(16))) u16 Pts[4][16 * 64];   // per-wave P^T
  const int tid = threadIdx.x;
  const int lane = tid & 63, wave = tid >> 6;
  const int quad = lane >> 4, l15 = lane & 15;
  const int lin = blockIdx.y * gridDim.x + blockIdx.x;
  const int h = lin & 31;
  const int pp = (lin >> 5) & 7;
  const int u = (lin >> 8) ? 15 - pp : pp;     // q-tile index
  const int hk = h >> 2;
  const int swz = 2 * (l15 & 7);               // even XOR swizzle for Pt units
  const int nt = 2 * (u + 1);                  // KV-64 tiles

  // Q fragments as B-operand: qf[n][ks], qrow = u*128 + wave*32 + n*16 + l15
  bf16x8 qf[2][4];
#pragma unroll
  for (int n = 0; n < 2; ++n) {
    const u16* qrow = Qb + (long)(u * 128 + wave * 32 + n * 16 + l15) * (HQ * HD)
                      + h * HD + quad * 8;
#pragma unroll
    for (int ks = 0; ks < 4; ++ks) qf[n][ks] = *(const bf16x8*)(qrow + ks * 32);
  }

  // stage K (64 kpos rows x 128d, 16 chunks/row, ^row&15) and
  //       V^T (128 d rows x 64 kpos, 8 chunks/row, ^row&7) for tile t
  auto stage = [&](int t) {
    const int b = t & 1;
#pragma unroll
    for (int it = 0; it < 4; ++it) {
      int c = tid + it * 256;
      int row = c >> 4, cc = c & 15, cs = cc ^ (row & 15);
      async_load16(Kb + (long)(t * 64 + row) * (HK * HD) + hk * HD + cs * 8,
                   (u16*)&Ks[b][0] + c * 8);
    }
#pragma unroll
    for (int it = 0; it < 4; ++it) {
      int c = tid + it * 256;
      int row = c >> 3, cc = c & 7, cs = cc ^ (row & 7);
      async_load16(Vt + (long)(hk * HD + row) * S_LEN + t * 64 + cs * 8,
                   (u16*)&Vs[b][0] + c * 8);
    }
  };

  float m_run[2] = {NEG_INF, NEG_INF}, l_run[2] = {0.f, 0.f};
  f32x4 oacc[8][2] = {};

  stage(0);
  __syncthreads();

  for (int t = 0; t < nt; ++t) {
    const int cur = t & 1;
    if (t + 1 < nt) stage(t + 1);

    // skip waves whose rows are entirely above this KV tile (fully masked)
    if (t * 64 <= u * 128 + wave * 32 + 31) {
      // ---- S^T = K @ Q^T : sc[tj][n], row=kpos(quad*4+r), col=qrow(l15) ----
      f32x4 sc[4][2] = {};
      __builtin_amdgcn_s_setprio(1);
#pragma unroll
      for (int ks = 0; ks < 4; ++ks)
#pragma unroll
        for (int tj = 0; tj < 4; ++tj) {
          int row = tj * 16 + l15;
          bf16x8 kf = *(const bf16x8*)(&Ks[cur][0] + row * 128
                                       + (((ks * 4 + quad) ^ (row & 15)) * 8));
          sc[tj][0] = mfma16(kf, qf[0][ks], sc[tj][0]);
          sc[tj][1] = mfma16(kf, qf[1][ks], sc[tj][1]);
        }
      __builtin_amdgcn_s_setprio(0);

      // ---- online softmax (defer-max, THR=8) ----
      const bool diag = (t >= 2 * u);
      const int kbase = t * 64 - u * 128;
#pragma unroll
      for (int n = 0; n < 2; ++n) {
        int qloc = wave * 32 + n * 16 + l15;
        if (diag) {
#pragma unroll
          for (int tj = 0; tj < 4; ++tj)
#pragma unroll
            for (int r = 0; r < 4; ++r)
              if (kbase + tj * 16 + quad * 4 + r > qloc) sc[tj][n][r] = NEG_INF;
        }
        float m = NEG_INF;
#pragma unroll
        for (int tj = 0; tj < 4; ++tj)
#pragma unroll
          for (int r = 0; r < 4; ++r) m = fmaxf(m, sc[tj][n][r]);
        m = fmaxf(m, __shfl_xor(m, 16));
        m = fmaxf(m, __shfl_xor(m, 32));
        if (!__all(m - m_run[n] <= 8.0f)) {
          float mnew = fmaxf(m_run[n], m);
          float alpha = __expf(m_run[n] - mnew);
          m_run[n] = mnew;
          l_run[n] *= alpha;
#pragma unroll
          for (int tj = 0; tj < 8; ++tj) oacc[tj][n] *= alpha;
        }
        float rs = 0.f;
#pragma unroll
        for (int tj = 0; tj < 4; ++tj)
#pragma unroll
          for (int r = 0; r < 4; ++r) {
            float p = __expf(sc[tj][n][r] - m_run[n]);
            sc[tj][n][r] = p;
            rs += p;
          }
        rs += __shfl_xor(rs, 16);
        rs += __shfl_xor(rs, 32);
        l_run[n] += rs;
      }

      // ---- P^T -> per-wave LDS (b64 writes), read back as B frags (b128) ----
      u16* pw = &Pts[wave][0];
      bf16x8 pf0[2], pf1[2];
#pragma unroll
      for (int tj = 0; tj < 4; ++tj) {
        union { u32 w[2]; uint2 u2; } pk;
        pk.w[0] = pack2bf(sc[tj][0][0], sc[tj][0][1]);
        pk.w[1] = pack2bf(sc[tj][0][2], sc[tj][0][3]);
        *(uint2*)(pw + l15 * 64 + (((tj * 4 + quad) ^ swz) * 4)) = pk.u2;
      }
      __asm__ volatile("s_waitcnt lgkmcnt(0)" ::: "memory");
#pragma unroll
      for (int ks = 0; ks < 2; ++ks)
        pf0[ks] = *(const bf16x8*)(pw + l15 * 64 + (((ks * 8 + quad * 2) ^ swz) * 4));
      __asm__ volatile("s_waitcnt lgkmcnt(0)" ::: "memory");
#pragma unroll
      for (int tj = 0; tj < 4; ++tj) {
        union { u32 w[2]; uint2 u2; } pk;
        pk.w[0] = pack2bf(sc[tj][1][0], sc[tj][1][1]);
        pk.w[1] = pack2bf(sc[tj][1][2], sc[tj][1][3]);
        *(uint2*)(pw + l15 * 64 + (((tj * 4 + quad) ^ swz) * 4)) = pk.u2;
      }
      __asm__ volatile("s_waitcnt lgkmcnt(0)" ::: "memory");
#pragma unroll
      for (int ks = 0; ks < 2; ++ks)
        pf1[ks] = *(const bf16x8*)(pw + l15 * 64 + (((ks * 8 + quad * 2) ^ swz) * 4));

      // ---- O^T += V^T @ P^T ----
      __builtin_amdgcn_s_setprio(1);
#pragma unroll
      for (int ks = 0; ks < 2; ++ks)
#pragma unroll
        for (int tj = 0; tj < 8; ++tj) {
          int row = tj * 16 + l15;
          bf16x8 vf = *(const bf16x8*)(&Vs[cur][0] + row * 64
                                       + (((ks * 4 + quad) ^ (row & 7)) * 8));
          oacc[tj][0] = mfma16(vf, pf0[ks], oacc[tj][0]);
          oacc[tj][1] = mfma16(vf, pf1[ks], oacc[tj][1]);
        }
      __builtin_amdgcn_s_setprio(0);
    }

    __syncthreads();   // vmcnt(0): stage(t+1) landed; publishes to all waves
  }

  // ---- epilogue: O^T tile row=d(quad*4+r), col=qrow(l15); pack 4 bf16 ----
#pragma unroll
  for (int n = 0; n < 2; ++n) {
    float inv_l = 1.0f / l_run[n];
    long grow = u * 128 + wave * 32 + n * 16 + l15;
#pragma unroll
    for (int tj = 0; tj < 8; ++tj) {
      int gcol = h * HD + tj * 16 + quad * 4;
      union { u32 w[2]; uint2 u2; } pk;
      pk.w[0] = pack2bf(oacc[tj][n][0] * inv_l, oacc[tj][n][1] * inv_l);
      pk.w[1] = pack2bf(oacc[tj][n][2] * inv_l, oacc[tj][n][3] * inv_l);
      *(uint2*)(Ob + grow * (HQ * HD) + gcol) = pk.u2;
    }
  }
}

// ---------- host ----------
#define MB (1024L * 1024L)

extern "C" void kernel_launch(void* const* d_in, const int* in_sizes, int n_in,
                              void* d_out, int out_size, void* d_ws, size_t ws_size,
                              hipStream_t stream) {
  const float* x    = (const float*)d_in[0];
  const float* fcos = (const float*)d_in[1];
  const float* fsin = (const float*)d_in[2];
  const float* wq   = (const float*)d_in[3];
  const float* wk   = (const float*)d_in[4];
  const float* wv   = (const float*)d_in[5];
  const float* wo   = (const float*)d_in[6];
  float* out = (float*)d_out;

  char* ws = (char*)d_ws;
  u16* wt    = (u16*)(ws + 0 * MB);     // 48 MB: QKV weights^T (6144,4096); reused for wo^T
  u16* xb    = (u16*)(ws + 48 * MB);    // 16 MB
  u16* QKVb  = (u16*)(ws + 64 * MB);    // 24 MB: (S, 6144) bf16
  u16* Qb    = (u16*)(ws + 88 * MB);    // 16 MB
  u16* Kb    = (u16*)(ws + 104 * MB);   // 4 MB
  u16* Vt    = (u16*)(ws + 108 * MB);   // 4 MB
  u16* attnb = (u16*)(ws + 112 * MB);   // 16 MB

  const int M = S_LEN, D = D_MODEL;

  // x -> bf16
  cvt_f32_bf16<<<(M * D) / 1024, 256, 0, stream>>>(x, xb, M * D);

  // weights^T (concat rows: wq^T | wk^T | wv^T)
  transpose_f32_bf16<<<dim3(D / 32, D / 32), dim3(32, 8), 0, stream>>>(wq, wt, D, HQ * HD);
  transpose_f32_bf16<<<dim3((HK * HD) / 32, D / 32), dim3(32, 8), 0, stream>>>(
      wk, wt + (long)(HQ * HD) * D, D, HK * HD);
  transpose_f32_bf16<<<dim3((HK * HD) / 32, D / 32), dim3(32, 8), 0, stream>>>(
      wv, wt + (long)(HQ * HD + HK * HD) * D, D, HK * HD);

  // fused QKV projection -> bf16  (B-direct GEMM, grid 32x16 = 512 wgs, 2/CU)
  gemm_bdir<192, true><<<dim3(NQKV / 192, M / 128), 256, 0, stream>>>(
      xb, wt, QKVb, NQKV, D);

  // RoPE (scale folded into Q) from QKV slices
  rope_bf16<<<(M * HQ * 64) / 256, 256, 0, stream>>>(
      QKVb, fcos, fsin, Qb, HQ, NQKV, 0, 0.08838834764831845f);
  rope_bf16<<<(M * HK * 64) / 256, 256, 0, stream>>>(
      QKVb, fcos, fsin, Kb, HK, NQKV, HQ * HD, 1.0f);
  // V^T from QKV slice
  transpose_bf16<<<dim3((HK * HD) / 32, M / 32), dim3(32, 8), 0, stream>>>(
      QKVb, Vt, M, HK * HD, NQKV, HQ * HD + HK * HD);

  // flash attention
  attn_fwd<<<dim3(16, HQ), 256, 0, stream>>>(Qb, Kb, Vt, attnb);

  // out = attn @ wo  (B-direct GEMM, grid 32x16 = 512 wgs, 2/CU)
  transpose_f32_bf16<<<dim3(D / 32, D / 32), dim3(32, 8), 0, stream>>>(wo, wt, HQ * HD, D);
  gemm_bdir<128, false><<<dim3(D / 128, M / 128), 256, 0, stream>>>(
      attnb, wt, out, D, HQ * HD);
}

// Round 6
// 507.337 us; speedup vs baseline: 1.0812x; 1.0812x over previous
//
#include <hip/hip_runtime.h>
#include <stdint.h>

typedef __bf16 bf16_t;
typedef bf16_t bf16x8 __attribute__((ext_vector_type(8)));
typedef float f32x4 __attribute__((ext_vector_type(4)));
typedef unsigned int u32;
typedef unsigned short u16;

#define DEV_INLINE __device__ __forceinline__

// ---------- constants ----------
#define S_LEN 2048
#define D_MODEL 4096
#define HQ 32
#define HK 8
#define HD 128
#define NQKV 6144   // HQ*HD + 2*HK*HD

DEV_INLINE u16 f2bf(float x) {
  union { float f; uint32_t u; } v; v.f = x;
  uint32_t r = v.u + 0x7FFFu + ((v.u >> 16) & 1u);  // RNE
  return (u16)(r >> 16);
}
DEV_INLINE float bf2f(u16 x) {
  union { uint32_t u; float f; } v; v.u = ((uint32_t)x) << 16;
  return v.f;
}
DEV_INLINE u32 pack2bf(float a, float b) {
  return (u32)f2bf(a) | ((u32)f2bf(b) << 16);
}

DEV_INLINE void async_load16(const void* g, void* l) {
  __builtin_amdgcn_global_load_lds(
      (const __attribute__((address_space(1))) u32*)g,
      (__attribute__((address_space(3))) u32*)l, 16, 0, 0);
}

DEV_INLINE f32x4 mfma16(bf16x8 a, bf16x8 b, f32x4 c) {
  return __builtin_amdgcn_mfma_f32_16x16x32_bf16(a, b, c, 0, 0, 0);
}

// ---------- elementwise f32 -> bf16 ----------
__global__ void cvt_f32_bf16(const float* __restrict__ in, u16* __restrict__ out, int n) {
  int i = (blockIdx.x * blockDim.x + threadIdx.x) * 4;
  if (i >= n) return;
  float4 v = *(const float4*)(in + i);
  union { u16 s[4]; uint2 u; } o;
  o.s[0] = f2bf(v.x); o.s[1] = f2bf(v.y); o.s[2] = f2bf(v.z); o.s[3] = f2bf(v.w);
  *(uint2*)(out + i) = o.u;
}

// ---------- transpose fp32 (R,C) -> bf16 (C,R), 64x64 tile ----------
// block (64,4); reads 256B/row, writes full 128B segments (was 64B partial).
__global__ void transpose_f32_bf16(const float* __restrict__ in, u16* __restrict__ out,
                                   int R, int C) {
  __shared__ float tile[64][65];
  int tx = threadIdx.x, ty = threadIdx.y;           // block (64,4)
  int c0 = blockIdx.x * 64, r0 = blockIdx.y * 64;
#pragma unroll
  for (int i = 0; i < 16; ++i)
    tile[ty + i * 4][tx] = in[(long)(r0 + ty + i * 4) * C + c0 + tx];
  __syncthreads();
#pragma unroll
  for (int i = 0; i < 16; ++i)
    out[(long)(c0 + ty + i * 4) * R + r0 + tx] = f2bf(tile[tx][ty + i * 4]);
}

// ---------- transpose bf16 (R, ld_in cols, slice [col_off, col_off+C)) -> (C, R) ----------
__global__ void transpose_bf16(const u16* __restrict__ in, u16* __restrict__ out,
                               int R, int C, int ld_in, int col_off) {
  __shared__ u16 tile[32][33];
  int tx = threadIdx.x, ty = threadIdx.y;           // block (32,8)
  int c0 = blockIdx.x * 32, r0 = blockIdx.y * 32;
#pragma unroll
  for (int i = 0; i < 4; ++i)
    tile[ty + i * 8][tx] = in[(long)(r0 + ty + i * 8) * ld_in + col_off + c0 + tx];
  __syncthreads();
#pragma unroll
  for (int i = 0; i < 4; ++i)
    out[(long)(c0 + ty + i * 8) * R + r0 + tx] = tile[tx][ty + i * 8];
}

// ---------- RoPE on bf16 (strided input slice) -> packed bf16 ----------
__global__ void rope_bf16(const u16* __restrict__ in, const float* __restrict__ cosb,
                          const float* __restrict__ sinb, u16* __restrict__ out,
                          int H, int ld_in, int col_off, float scale) {
  int idx = blockIdx.x * blockDim.x + threadIdx.x;   // over S*H*64
  int j = idx & 63;
  int sh = idx >> 6;            // s*H + h
  int s = sh / H, h = sh - s * H;
  const u16* ip = in + (long)s * ld_in + col_off + h * HD;
  union { u32 u; u16 s2[2]; } v; v.u = *(const u32*)(ip + 2 * j);
  float q0 = bf2f(v.s2[0]), q1 = bf2f(v.s2[1]);
  float c = cosb[s * 64 + j], sn = sinb[s * 64 + j];
  union { u16 s2[2]; u32 u; } o;
  o.s2[0] = f2bf((q0 * c - q1 * sn) * scale);
  o.s2[1] = f2bf((q0 * sn + q1 * c) * scale);
  *(u32*)(out + (long)sh * HD + 2 * j) = o.u;
}

#define BARRIER() asm volatile("s_barrier" ::: "memory")
#define WAIT_VM(N) asm volatile("s_waitcnt vmcnt(" #N ")" ::: "memory")

// ---------- GEMM v6: BM=128, 4 waves, 2-slot ring, 2 blocks/CU ----------
// C(M,N) = A(M,K)bf16 @ Bt(N,K)^T.  256 thr (4 waves, 1M x 4N), wave tile
// 128 x (BN/4).  A+B staged via global_load_lds into a 2-slot LDS ring
// (r4's verified chunk-swizzle pattern).  stage(t+1) issued at tile START;
// vmcnt(0)+barrier at tile end (drain issued ~1000cy after loads -> cheap).
// Grid 512 -> 2 blocks/CU: two independent barrier domains so one block's
// ds_read burst overlaps the other's MFMA burst (r4 counters showed a single
// phase-locked block serializes LDS-port time + MFMA time; r5 confirmed
// 2 blocks/CU co-residency at this LDS size).
// Ring-2 safety (same as attn): stage writes slot (t+1)&1 while reads hit
// slot t&1; end-of-tile vmcnt(0) lands t+1, barrier publishes it and ensures
// all waves finished reading slot t&1 before iter t+1 stages t+2 into it.
template <int BN, bool BF16OUT>
__global__ __launch_bounds__(256, 2) void gemm_db(
    const u16* __restrict__ A, const u16* __restrict__ Bt, void* __restrict__ Cv,
    int N, int K) {
  constexpr int NF = BN / 64;            // n-frags per wave (3 or 2)
  constexpr int BPT = (BN * 4) / 256;    // B 16B-chunks per thread (3 or 2)
  constexpr int LDSU = (128 + BN) * 32;  // u16 per ring slot

  __shared__ __attribute__((aligned(16))) u16 lds[2][LDSU];

  const int tid = threadIdx.x;
  const int lane = tid & 63, wave = tid >> 6;
  const int quad = lane >> 4, l15 = lane & 15;

  // T1: XCD-chunked swizzle (grid 512 = 8 XCDs x 64; bm = 2 panels/XCD -> 2MB
  // A resident per XCD L2; B streams via L3)
  const int gx = gridDim.x;
  const int bid = blockIdx.y * gx + blockIdx.x;
  const int cpx = (gx * gridDim.y) >> 3;
  const int sw = (bid & 7) * cpx + (bid >> 3);
  const int bn = sw % gx, bm = sw / gx;

  const long arow = (long)bm * 128, brow = (long)bn * BN;
  const int NT = K >> 5;

  // chunk swizzle: LDS chunk cc of row holds src chunk cc ^ ((row>>1)&3)
  auto stage = [&](int ts) {
    const int k0 = ts * 32;
    u16* base = &lds[ts & 1][0];
#pragma unroll
    for (int j = 0; j < 2; ++j) {
      int c = tid + j * 256;
      int row = c >> 2, cc = c & 3, cs = cc ^ ((row >> 1) & 3);
      async_load16(A + (arow + row) * (long)K + k0 + cs * 8, base + c * 8);
    }
#pragma unroll
    for (int j = 0; j < BPT; ++j) {
      int c = tid + j * 256;
      int row = c >> 2, cc = c & 3, cs = cc ^ ((row >> 1) & 3);
      async_load16(Bt + (brow + row) * (long)K + k0 + cs * 8,
                   base + 4096 + c * 8);
    }
  };
  auto rdfrag = [&](const u16* base, int row) -> bf16x8 {
    return *(const bf16x8*)(base + row * 32 + ((quad ^ ((row >> 1) & 3)) * 8));
  };

  f32x4 acc[8][NF] = {};

  stage(0);
  WAIT_VM(0);
  BARRIER();

  for (int t = 0; t < NT; ++t) {
    if (t + 1 < NT) stage(t + 1);
    const u16* Ab = &lds[t & 1][0];
    const u16* Bb = Ab + 4096;
    bf16x8 bfr[NF];
#pragma unroll
    for (int j = 0; j < NF; ++j)
      bfr[j] = rdfrag(Bb, wave * (NF * 16) + j * 16 + l15);
    __builtin_amdgcn_s_setprio(1);
#pragma unroll
    for (int i = 0; i < 8; ++i) {
      bf16x8 af = rdfrag(Ab, i * 16 + l15);
#pragma unroll
      for (int j = 0; j < NF; ++j)
        acc[i][j] = mfma16(af, bfr[j], acc[i][j]);
    }
    __builtin_amdgcn_s_setprio(0);
    WAIT_VM(0);
    BARRIER();
  }

  // epilogue: C row from A (quad*4+r), col from B (l15)
#pragma unroll
  for (int i = 0; i < 8; ++i) {
    const long row = (long)bm * 128 + i * 16 + quad * 4;
#pragma unroll
    for (int j = 0; j < NF; ++j) {
      const int col = bn * BN + wave * (NF * 16) + j * 16 + l15;
      if constexpr (BF16OUT) {
        u16* C = (u16*)Cv;
#pragma unroll
        for (int r = 0; r < 4; ++r) C[(row + r) * N + col] = f2bf(acc[i][j][r]);
      } else {
        float* C = (float*)Cv;
#pragma unroll
        for (int r = 0; r < 4; ++r) C[(row + r) * N + col] = acc[i][j][r];
      }
    }
  }
}

// ---------- flash attention v2 (unchanged from r4) ----------
#define NEG_INF -1e30f
__global__ __launch_bounds__(256, 2) void attn_fwd(
    const u16* __restrict__ Qb, const u16* __restrict__ Kb,
    const u16* __restrict__ Vt, u16* __restrict__ Ob) {
  __shared__ __attribute__((aligned(16))) u16 Ks[2][64 * 128];   // kpos-major
  __shared__ __attribute__((aligned(16))) u16 Vs[2][128 * 64];   // d-major (V^T)
  __shared__ __attribute__((aligned(16))) u16 Pts[4][16 * 64];   // per-wave P^T
  const int tid = threadIdx.x;
  const int lane = tid & 63, wave = tid >> 6;
  const int quad = lane >> 4, l15 = lane & 15;
  const int lin = blockIdx.y * gridDim.x + blockIdx.x;
  const int h = lin & 31;
  const int pp = (lin >> 5) & 7;
  const int u = (lin >> 8) ? 15 - pp : pp;     // q-tile index
  const int hk = h >> 2;
  const int swz = 2 * (l15 & 7);               // even XOR swizzle for Pt units
  const int nt = 2 * (u + 1);                  // KV-64 tiles

  // Q fragments as B-operand: qf[n][ks], qrow = u*128 + wave*32 + n*16 + l15
  bf16x8 qf[2][4];
#pragma unroll
  for (int n = 0; n < 2; ++n) {
    const u16* qrow = Qb + (long)(u * 128 + wave * 32 + n * 16 + l15) * (HQ * HD)
                      + h * HD + quad * 8;
#pragma unroll
    for (int ks = 0; ks < 4; ++ks) qf[n][ks] = *(const bf16x8*)(qrow + ks * 32);
  }

  // stage K (64 kpos rows x 128d, 16 chunks/row, ^row&15) and
  //       V^T (128 d rows x 64 kpos, 8 chunks/row, ^row&7) for tile t
  auto stage = [&](int t) {
    const int b = t & 1;
#pragma unroll
    for (int it = 0; it < 4; ++it) {
      int c = tid + it * 256;
      int row = c >> 4, cc = c & 15, cs = cc ^ (row & 15);
      async_load16(Kb + (long)(t * 64 + row) * (HK * HD) + hk * HD + cs * 8,
                   (u16*)&Ks[b][0] + c * 8);
    }
#pragma unroll
    for (int it = 0; it < 4; ++it) {
      int c = tid + it * 256;
      int row = c >> 3, cc = c & 7, cs = cc ^ (row & 7);
      async_load16(Vt + (long)(hk * HD + row) * S_LEN + t * 64 + cs * 8,
                   (u16*)&Vs[b][0] + c * 8);
    }
  };

  float m_run[2] = {NEG_INF, NEG_INF}, l_run[2] = {0.f, 0.f};
  f32x4 oacc[8][2] = {};

  stage(0);
  __syncthreads();

  for (int t = 0; t < nt; ++t) {
    const int cur = t & 1;
    if (t + 1 < nt) stage(t + 1);

    // skip waves whose rows are entirely above this KV tile (fully masked)
    if (t * 64 <= u * 128 + wave * 32 + 31) {
      // ---- S^T = K @ Q^T : sc[tj][n], row=kpos(quad*4+r), col=qrow(l15) ----
      f32x4 sc[4][2] = {};
      __builtin_amdgcn_s_setprio(1);
#pragma unroll
      for (int ks = 0; ks < 4; ++ks)
#pragma unroll
        for (int tj = 0; tj < 4; ++tj) {
          int row = tj * 16 + l15;
          bf16x8 kf = *(const bf16x8*)(&Ks[cur][0] + row * 128
                                       + (((ks * 4 + quad) ^ (row & 15)) * 8));
          sc[tj][0] = mfma16(kf, qf[0][ks], sc[tj][0]);
          sc[tj][1] = mfma16(kf, qf[1][ks], sc[tj][1]);
        }
      __builtin_amdgcn_s_setprio(0);

      // ---- online softmax (defer-max, THR=8) ----
      const bool diag = (t >= 2 * u);
      const int kbase = t * 64 - u * 128;
#pragma unroll
      for (int n = 0; n < 2; ++n) {
        int qloc = wave * 32 + n * 16 + l15;
        if (diag) {
#pragma unroll
          for (int tj = 0; tj < 4; ++tj)
#pragma unroll
            for (int r = 0; r < 4; ++r)
              if (kbase + tj * 16 + quad * 4 + r > qloc) sc[tj][n][r] = NEG_INF;
        }
        float m = NEG_INF;
#pragma unroll
        for (int tj = 0; tj < 4; ++tj)
#pragma unroll
          for (int r = 0; r < 4; ++r) m = fmaxf(m, sc[tj][n][r]);
        m = fmaxf(m, __shfl_xor(m, 16));
        m = fmaxf(m, __shfl_xor(m, 32));
        if (!__all(m - m_run[n] <= 8.0f)) {
          float mnew = fmaxf(m_run[n], m);
          float alpha = __expf(m_run[n] - mnew);
          m_run[n] = mnew;
          l_run[n] *= alpha;
#pragma unroll
          for (int tj = 0; tj < 8; ++tj) oacc[tj][n] *= alpha;
        }
        float rs = 0.f;
#pragma unroll
        for (int tj = 0; tj < 4; ++tj)
#pragma unroll
          for (int r = 0; r < 4; ++r) {
            float p = __expf(sc[tj][n][r] - m_run[n]);
            sc[tj][n][r] = p;
            rs += p;
          }
        rs += __shfl_xor(rs, 16);
        rs += __shfl_xor(rs, 32);
        l_run[n] += rs;
      }

      // ---- P^T -> per-wave LDS (b64 writes), read back as B frags (b128) ----
      u16* pw = &Pts[wave][0];
      bf16x8 pf0[2], pf1[2];
#pragma unroll
      for (int tj = 0; tj < 4; ++tj) {
        union { u32 w[2]; uint2 u2; } pk;
        pk.w[0] = pack2bf(sc[tj][0][0], sc[tj][0][1]);
        pk.w[1] = pack2bf(sc[tj][0][2], sc[tj][0][3]);
        *(uint2*)(pw + l15 * 64 + (((tj * 4 + quad) ^ swz) * 4)) = pk.u2;
      }
      __asm__ volatile("s_waitcnt lgkmcnt(0)" ::: "memory");
#pragma unroll
      for (int ks = 0; ks < 2; ++ks)
        pf0[ks] = *(const bf16x8*)(pw + l15 * 64 + (((ks * 8 + quad * 2) ^ swz) * 4));
      __asm__ volatile("s_waitcnt lgkmcnt(0)" ::: "memory");
#pragma unroll
      for (int tj = 0; tj < 4; ++tj) {
        union { u32 w[2]; uint2 u2; } pk;
        pk.w[0] = pack2bf(sc[tj][1][0], sc[tj][1][1]);
        pk.w[1] = pack2bf(sc[tj][1][2], sc[tj][1][3]);
        *(uint2*)(pw + l15 * 64 + (((tj * 4 + quad) ^ swz) * 4)) = pk.u2;
      }
      __asm__ volatile("s_waitcnt lgkmcnt(0)" ::: "memory");
#pragma unroll
      for (int ks = 0; ks < 2; ++ks)
        pf1[ks] = *(const bf16x8*)(pw + l15 * 64 + (((ks * 8 + quad * 2) ^ swz) * 4));

      // ---- O^T += V^T @ P^T ----
      __builtin_amdgcn_s_setprio(1);
#pragma unroll
      for (int ks = 0; ks < 2; ++ks)
#pragma unroll
        for (int tj = 0; tj < 8; ++tj) {
          int row = tj * 16 + l15;
          bf16x8 vf = *(const bf16x8*)(&Vs[cur][0] + row * 64
                                       + (((ks * 4 + quad) ^ (row & 7)) * 8));
          oacc[tj][0] = mfma16(vf, pf0[ks], oacc[tj][0]);
          oacc[tj][1] = mfma16(vf, pf1[ks], oacc[tj][1]);
        }
      __builtin_amdgcn_s_setprio(0);
    }

    __syncthreads();   // vmcnt(0): stage(t+1) landed; publishes to all waves
  }

  // ---- epilogue: O^T tile row=d(quad*4+r), col=qrow(l15); pack 4 bf16 ----
#pragma unroll
  for (int n = 0; n < 2; ++n) {
    float inv_l = 1.0f / l_run[n];
    long grow = u * 128 + wave * 32 + n * 16 + l15;
#pragma unroll
    for (int tj = 0; tj < 8; ++tj) {
      int gcol = h * HD + tj * 16 + quad * 4;
      union { u32 w[2]; uint2 u2; } pk;
      pk.w[0] = pack2bf(oacc[tj][n][0] * inv_l, oacc[tj][n][1] * inv_l);
      pk.w[1] = pack2bf(oacc[tj][n][2] * inv_l, oacc[tj][n][3] * inv_l);
      *(uint2*)(Ob + grow * (HQ * HD) + gcol) = pk.u2;
    }
  }
}

// ---------- host ----------
#define MB (1024L * 1024L)

extern "C" void kernel_launch(void* const* d_in, const int* in_sizes, int n_in,
                              void* d_out, int out_size, void* d_ws, size_t ws_size,
                              hipStream_t stream) {
  const float* x    = (const float*)d_in[0];
  const float* fcos = (const float*)d_in[1];
  const float* fsin = (const float*)d_in[2];
  const float* wq   = (const float*)d_in[3];
  const float* wk   = (const float*)d_in[4];
  const float* wv   = (const float*)d_in[5];
  const float* wo   = (const float*)d_in[6];
  float* out = (float*)d_out;

  char* ws = (char*)d_ws;
  u16* wt    = (u16*)(ws + 0 * MB);     // 48 MB: QKV weights^T (6144,4096); reused for wo^T
  u16* xb    = (u16*)(ws + 48 * MB);    // 16 MB
  u16* QKVb  = (u16*)(ws + 64 * MB);    // 24 MB: (S, 6144) bf16
  u16* Qb    = (u16*)(ws + 88 * MB);    // 16 MB
  u16* Kb    = (u16*)(ws + 104 * MB);   // 4 MB
  u16* Vt    = (u16*)(ws + 108 * MB);   // 4 MB
  u16* attnb = (u16*)(ws + 112 * MB);   // 16 MB

  const int M = S_LEN, D = D_MODEL;

  // x -> bf16
  cvt_f32_bf16<<<(M * D) / 1024, 256, 0, stream>>>(x, xb, M * D);

  // weights^T (concat rows: wq^T | wk^T | wv^T), 64x64-tile transpose
  transpose_f32_bf16<<<dim3(D / 64, D / 64), dim3(64, 4), 0, stream>>>(wq, wt, D, HQ * HD);
  transpose_f32_bf16<<<dim3((HK * HD) / 64, D / 64), dim3(64, 4), 0, stream>>>(
      wk, wt + (long)(HQ * HD) * D, D, HK * HD);
  transpose_f32_bf16<<<dim3((HK * HD) / 64, D / 64), dim3(64, 4), 0, stream>>>(
      wv, wt + (long)(HQ * HD + HK * HD) * D, D, HK * HD);

  // fused QKV projection -> bf16  (gemm_db, grid 32x16 = 512 wgs, 2 blocks/CU)
  gemm_db<192, true><<<dim3(NQKV / 192, M / 128), 256, 0, stream>>>(
      xb, wt, QKVb, NQKV, D);

  // RoPE (scale folded into Q) from QKV slices
  rope_bf16<<<(M * HQ * 64) / 256, 256, 0, stream>>>(
      QKVb, fcos, fsin, Qb, HQ, NQKV, 0, 0.08838834764831845f);
  rope_bf16<<<(M * HK * 64) / 256, 256, 0, stream>>>(
      QKVb, fcos, fsin, Kb, HK, NQKV, HQ * HD, 1.0f);
  // V^T from QKV slice
  transpose_bf16<<<dim3((HK * HD) / 32, M / 32), dim3(32, 8), 0, stream>>>(
      QKVb, Vt, M, HK * HD, NQKV, HQ * HD + HK * HD);

  // flash attention
  attn_fwd<<<dim3(16, HQ), 256, 0, stream>>>(Qb, Kb, Vt, attnb);

  // out = attn @ wo  (gemm_db, grid 32x16 = 512 wgs, 2 blocks/CU)
  transpose_f32_bf16<<<dim3(D / 64, D / 64), dim3(64, 4), 0, stream>>>(wo, wt, HQ * HD, D);
  gemm_db<128, false><<<dim3(D / 128, M / 128), 256, 0, stream>>>(
      attnb, wt, out, D, HQ * HD);
}

// Round 7
// 483.439 us; speedup vs baseline: 1.1347x; 1.0494x over previous
//
#include <hip/hip_runtime.h>
#include <stdint.h>

typedef __bf16 bf16_t;
typedef bf16_t bf16x8 __attribute__((ext_vector_type(8)));
typedef float f32x4 __attribute__((ext_vector_type(4)));
typedef unsigned int u32;
typedef unsigned short u16;

#define DEV_INLINE __device__ __forceinline__

// ---------- constants ----------
#define S_LEN 2048
#define D_MODEL 4096
#define HQ 32
#define HK 8
#define HD 128
#define NQKV 6144   // HQ*HD + 2*HK*HD

DEV_INLINE u16 f2bf(float x) {
  union { float f; uint32_t u; } v; v.f = x;
  uint32_t r = v.u + 0x7FFFu + ((v.u >> 16) & 1u);  // RNE
  return (u16)(r >> 16);
}
DEV_INLINE float bf2f(u16 x) {
  union { uint32_t u; float f; } v; v.u = ((uint32_t)x) << 16;
  return v.f;
}
DEV_INLINE u32 pack2bf(float a, float b) {
  return (u32)f2bf(a) | ((u32)f2bf(b) << 16);
}

DEV_INLINE void async_load16(const void* g, void* l) {
  __builtin_amdgcn_global_load_lds(
      (const __attribute__((address_space(1))) u32*)g,
      (__attribute__((address_space(3))) u32*)l, 16, 0, 0);
}

DEV_INLINE f32x4 mfma16(bf16x8 a, bf16x8 b, f32x4 c) {
  return __builtin_amdgcn_mfma_f32_16x16x32_bf16(a, b, c, 0, 0, 0);
}

// ---------- elementwise f32 -> bf16 ----------
__global__ void cvt_f32_bf16(const float* __restrict__ in, u16* __restrict__ out, int n) {
  int i = (blockIdx.x * blockDim.x + threadIdx.x) * 4;
  if (i >= n) return;
  float4 v = *(const float4*)(in + i);
  union { u16 s[4]; uint2 u; } o;
  o.s[0] = f2bf(v.x); o.s[1] = f2bf(v.y); o.s[2] = f2bf(v.z); o.s[3] = f2bf(v.w);
  *(uint2*)(out + i) = o.u;
}

// ---------- transpose fp32 (R,C) -> bf16 (C,R), 64x64 tile ----------
__global__ void transpose_f32_bf16(const float* __restrict__ in, u16* __restrict__ out,
                                   int R, int C) {
  __shared__ float tile[64][65];
  int tx = threadIdx.x, ty = threadIdx.y;           // block (64,4)
  int c0 = blockIdx.x * 64, r0 = blockIdx.y * 64;
#pragma unroll
  for (int i = 0; i < 16; ++i)
    tile[ty + i * 4][tx] = in[(long)(r0 + ty + i * 4) * C + c0 + tx];
  __syncthreads();
#pragma unroll
  for (int i = 0; i < 16; ++i)
    out[(long)(c0 + ty + i * 4) * R + r0 + tx] = f2bf(tile[tx][ty + i * 4]);
}

// ---------- transpose bf16 (R, ld_in cols, slice [col_off, col_off+C)) -> (C, R) ----------
__global__ void transpose_bf16(const u16* __restrict__ in, u16* __restrict__ out,
                               int R, int C, int ld_in, int col_off) {
  __shared__ u16 tile[32][33];
  int tx = threadIdx.x, ty = threadIdx.y;           // block (32,8)
  int c0 = blockIdx.x * 32, r0 = blockIdx.y * 32;
#pragma unroll
  for (int i = 0; i < 4; ++i)
    tile[ty + i * 8][tx] = in[(long)(r0 + ty + i * 8) * ld_in + col_off + c0 + tx];
  __syncthreads();
#pragma unroll
  for (int i = 0; i < 4; ++i)
    out[(long)(c0 + ty + i * 8) * R + r0 + tx] = tile[tx][ty + i * 8];
}

// ---------- RoPE on bf16 (strided input slice) -> packed bf16 ----------
__global__ void rope_bf16(const u16* __restrict__ in, const float* __restrict__ cosb,
                          const float* __restrict__ sinb, u16* __restrict__ out,
                          int H, int ld_in, int col_off, float scale) {
  int idx = blockIdx.x * blockDim.x + threadIdx.x;   // over S*H*64
  int j = idx & 63;
  int sh = idx >> 6;            // s*H + h
  int s = sh / H, h = sh - s * H;
  const u16* ip = in + (long)s * ld_in + col_off + h * HD;
  union { u32 u; u16 s2[2]; } v; v.u = *(const u32*)(ip + 2 * j);
  float q0 = bf2f(v.s2[0]), q1 = bf2f(v.s2[1]);
  float c = cosb[s * 64 + j], sn = sinb[s * 64 + j];
  union { u16 s2[2]; u32 u; } o;
  o.s2[0] = f2bf((q0 * c - q1 * sn) * scale);
  o.s2[1] = f2bf((q0 * sn + q1 * c) * scale);
  *(u32*)(out + (long)sh * HD + 2 * j) = o.u;
}

#define BARRIER() asm volatile("s_barrier" ::: "memory")
#define WAIT_VM(N) asm volatile("s_waitcnt vmcnt(" #N ")" ::: "memory")

// ---------- GEMM v7: r4 geometry + one-tile register prefetch ----------
// BM=256, BK=32, 4-slot LDS ring, 8 waves (512 thr), grid 256 = 1 block/CU.
// r4 post-mortem: 1912 cyc/K-tile vs ~520 cyc of port occupancy -> the gap is
// per-tile ds_read->MFMA latency with only 2 waves/SIMD. Fix: during tile t,
// ds_read tile t+1's A-frags into a second register bank; tile t's MFMAs use
// the bank filled last tile (no lgkm stall; LDS service overlaps MFMA).
// QKV (BN=192): prefetch A only (VGPR budget: acc 96 + 2x8 frags + fbl);
// proj (BN=128): prefetch A and B.
// Waits: per-tile vmcnt(LPT) leaves only stage(t+3) outstanding => stage(t+2)
// (issued 2 tiles earlier) retired -> next tile's prefetch reads are valid;
// trailing s_barrier publishes cross-wave. Tail (stages stop): NT-3 uses
// vmcnt(0); NT-2/NT-1 need no wait.
// WAR: slot (t+3)&3 = (t-1)&3; its last reads were consumed by MFMAs before
// the end-of-(t-1)/(t) barriers; stage(t+3) issues after. [ring logic as r4]
#define VML() do { if constexpr (LPT == 4) { WAIT_VM(4); } else { WAIT_VM(3); } } while (0)

#define KTILE(T, FAC, FAN, FBC, FBN, DO_READ, DO_STAGE, WMODE)            \
  {                                                                       \
    bf16x8 fbl[NF];                                                       \
    if constexpr (!PFB) {                                                 \
      const u16* Bb_ = &lds[(T) & 3][8192];                               \
      _Pragma("unroll")                                                   \
      for (int j = 0; j < NF; ++j)                                        \
        fbl[j] = rdfrag(Bb_, wc * WCOLS + j * 16 + l15);                  \
    }                                                                     \
    if (DO_READ) {                                                        \
      const u16* An_ = &lds[((T) + 1) & 3][0];                            \
      _Pragma("unroll")                                                   \
      for (int i = 0; i < MF; ++i)                                        \
        FAN[i] = rdfrag(An_, wr * MROWS + i * 16 + l15);                  \
      if constexpr (PFB) {                                                \
        _Pragma("unroll")                                                 \
        for (int j = 0; j < NF; ++j)                                      \
          FBN[j] = rdfrag(An_ + 8192, wc * WCOLS + j * 16 + l15);         \
      }                                                                   \
    }                                                                     \
    if (DO_STAGE) stageAB((T) + 3);                                       \
    __builtin_amdgcn_s_setprio(1);                                        \
    _Pragma("unroll")                                                     \
    for (int i = 0; i < MF; ++i)                                          \
      _Pragma("unroll")                                                   \
      for (int j = 0; j < NF; ++j) {                                      \
        if constexpr (PFB) acc[i][j] = mfma16(FAC[i], FBC[j], acc[i][j]); \
        else               acc[i][j] = mfma16(FAC[i], fbl[j], acc[i][j]); \
      }                                                                   \
    __builtin_amdgcn_s_setprio(0);                                        \
    if ((WMODE) == 0) { VML(); }                                          \
    else if ((WMODE) == 1) { WAIT_VM(0); }                                \
    BARRIER();                                                            \
  }

// C(M,N) = A(M,K)bf16 @ Bt(N,K)^T.
// BN=192: waves 2Mx4N, wave tile 128x48 (QKV, grid 32x8 = 256 wgs).
// BN=128: waves 4Mx2N, wave tile 64x64  (proj, grid 32x8 = 256 wgs).
template <int BN, int WM, bool BF16OUT>
__global__ __launch_bounds__(512, 2) void gemm_pf(
    const u16* __restrict__ A, const u16* __restrict__ Bt, void* __restrict__ Cv,
    int N, int K) {
  constexpr int WN = 8 / WM;
  constexpr int MROWS = 256 / WM;       // per-wave M rows
  constexpr int MF = MROWS / 16;        // m-frags per wave
  constexpr int NF = BN / (WN * 16);    // n-frags per wave
  constexpr int WCOLS = NF * 16;        // per-wave N cols
  constexpr int BCH = BN * 4;           // real B 16B-chunks per tile
  constexpr int BISS = (BCH + 511) / 512;   // B loads/thread (dup pad for 192)
  constexpr int LPT = 2 + BISS;         // loads per thread per tile (4 or 3)
  constexpr bool PFB = (BN == 128);     // prefetch B regs too (VGPR budget)
  constexpr int LDSU = (256 + BN) * 32; // u16 per ring slot

  __shared__ __attribute__((aligned(16))) u16 lds[4][LDSU];

  const int tid = threadIdx.x;
  const int lane = tid & 63;
  const int wave = tid >> 6;
  const int quad = lane >> 4, l15 = lane & 15;
  const int wr = wave / WN, wc = wave % WN;

  // T1: XCD-chunked swizzle (grid 256 = 8 XCDs x 32; bm = bid&7 -> one A-panel
  // resident per XCD L2)
  const int gx = gridDim.x;
  const int bid = blockIdx.y * gx + blockIdx.x;
  const int cpx = (gx * gridDim.y) >> 3;
  const int sw = (bid & 7) * cpx + (bid >> 3);
  const int bn = sw % gx, bm = sw / gx;

  const long arow = (long)bm * 256, brow = (long)bn * BN;
  const int NT = K >> 5;

  // chunk swizzle: LDS chunk cc of row holds src chunk cc ^ ((row>>1)&3).
  // BN=192: B chunks 512..767 loaded twice (same src, same dest) -> benign
  // dup keeps per-wave VMEM issue uniform so vmcnt constants hold.
  auto stageAB = [&](int ts) {
    const int bs = ts & 3;
    const int k0 = ts * 32;
#pragma unroll
    for (int j = 0; j < 2; ++j) {
      int c = tid + j * 512;
      int row = c >> 2, cc = c & 3, cs = cc ^ ((row >> 1) & 3);
      async_load16(A + (arow + row) * (long)K + k0 + cs * 8,
                   (u16*)&lds[bs][0] + c * 8);
    }
#pragma unroll
    for (int j = 0; j < BISS; ++j) {
      int c = tid + j * 512;
      int cd = (c < BCH) ? c : c - 256;
      int row = cd >> 2, cc = cd & 3, cs = cc ^ ((row >> 1) & 3);
      async_load16(Bt + (brow + row) * (long)K + k0 + cs * 8,
                   (u16*)&lds[bs][8192] + cd * 8);
    }
  };
  auto rdfrag = [&](const u16* base, int row) -> bf16x8 {
    return *(const bf16x8*)(base + row * 32 + ((quad ^ ((row >> 1) & 3)) * 8));
  };

  f32x4 acc[MF][NF] = {};
  bf16x8 fa0[MF], fa1[MF], fb0[NF], fb1[NF];

  // prologue: stage tiles 0..2; tile 0 landed (vmcnt leaves newest 2 tiles);
  // barrier publishes; then fill bank0 with tile 0's frags.
  stageAB(0); stageAB(1); stageAB(2);
  if constexpr (LPT == 4) { WAIT_VM(8); } else { WAIT_VM(6); }
  BARRIER();
  {
    const u16* Ab_ = &lds[0][0];
#pragma unroll
    for (int i = 0; i < MF; ++i) fa0[i] = rdfrag(Ab_, wr * MROWS + i * 16 + l15);
    if constexpr (PFB) {
#pragma unroll
      for (int j = 0; j < NF; ++j)
        fb0[j] = rdfrag(Ab_ + 8192, wc * WCOLS + j * 16 + l15);
    }
  }

  int t = 0;
  for (; t < NT - 4; t += 2) {
    KTILE(t,     fa0, fa1, fb0, fb1, true, true, 0);
    KTILE(t + 1, fa1, fa0, fb1, fb0, true, true, 0);
  }
  // tail: tiles NT-4..NT-1 (NT even, banks stay aligned)
  KTILE(t,     fa0, fa1, fb0, fb1, true,  true,  0);  // NT-4: stage(NT-1)
  KTILE(t + 1, fa1, fa0, fb1, fb0, true,  false, 1);  // NT-3: vm0 (stages stopped)
  KTILE(t + 2, fa0, fa1, fb0, fb1, true,  false, 2);  // NT-2
  KTILE(t + 3, fa1, fa0, fb1, fb0, false, false, 2);  // NT-1
  (void)t;

  // epilogue: C row from A (quad*4+r), col from B (l15)
#pragma unroll
  for (int i = 0; i < MF; ++i) {
    const long row = (long)bm * 256 + wr * MROWS + i * 16 + quad * 4;
#pragma unroll
    for (int j = 0; j < NF; ++j) {
      const int col = bn * BN + wc * WCOLS + j * 16 + l15;
      if constexpr (BF16OUT) {
        u16* C = (u16*)Cv;
#pragma unroll
        for (int r = 0; r < 4; ++r) C[(row + r) * N + col] = f2bf(acc[i][j][r]);
      } else {
        float* C = (float*)Cv;
#pragma unroll
        for (int r = 0; r < 4; ++r) C[(row + r) * N + col] = acc[i][j][r];
      }
    }
  }
}

// ---------- flash attention v2 (unchanged from r4) ----------
#define NEG_INF -1e30f
__global__ __launch_bounds__(256, 2) void attn_fwd(
    const u16* __restrict__ Qb, const u16* __restrict__ Kb,
    const u16* __restrict__ Vt, u16* __restrict__ Ob) {
  __shared__ __attribute__((aligned(16))) u16 Ks[2][64 * 128];   // kpos-major
  __shared__ __attribute__((aligned(16))) u16 Vs[2][128 * 64];   // d-major (V^T)
  __shared__ __attribute__((aligned(16))) u16 Pts[4][16 * 64];   // per-wave P^T
  const int tid = threadIdx.x;
  const int lane = tid & 63, wave = tid >> 6;
  const int quad = lane >> 4, l15 = lane & 15;
  const int lin = blockIdx.y * gridDim.x + blockIdx.x;
  const int h = lin & 31;
  const int pp = (lin >> 5) & 7;
  const int u = (lin >> 8) ? 15 - pp : pp;     // q-tile index
  const int hk = h >> 2;
  const int swz = 2 * (l15 & 7);               // even XOR swizzle for Pt units
  const int nt = 2 * (u + 1);                  // KV-64 tiles

  // Q fragments as B-operand: qf[n][ks], qrow = u*128 + wave*32 + n*16 + l15
  bf16x8 qf[2][4];
#pragma unroll
  for (int n = 0; n < 2; ++n) {
    const u16* qrow = Qb + (long)(u * 128 + wave * 32 + n * 16 + l15) * (HQ * HD)
                      + h * HD + quad * 8;
#pragma unroll
    for (int ks = 0; ks < 4; ++ks) qf[n][ks] = *(const bf16x8*)(qrow + ks * 32);
  }

  // stage K (64 kpos rows x 128d, 16 chunks/row, ^row&15) and
  //       V^T (128 d rows x 64 kpos, 8 chunks/row, ^row&7) for tile t
  auto stage = [&](int t) {
    const int b = t & 1;
#pragma unroll
    for (int it = 0; it < 4; ++it) {
      int c = tid + it * 256;
      int row = c >> 4, cc = c & 15, cs = cc ^ (row & 15);
      async_load16(Kb + (long)(t * 64 + row) * (HK * HD) + hk * HD + cs * 8,
                   (u16*)&Ks[b][0] + c * 8);
    }
#pragma unroll
    for (int it = 0; it < 4; ++it) {
      int c = tid + it * 256;
      int row = c >> 3, cc = c & 7, cs = cc ^ (row & 7);
      async_load16(Vt + (long)(hk * HD + row) * S_LEN + t * 64 + cs * 8,
                   (u16*)&Vs[b][0] + c * 8);
    }
  };

  float m_run[2] = {NEG_INF, NEG_INF}, l_run[2] = {0.f, 0.f};
  f32x4 oacc[8][2] = {};

  stage(0);
  __syncthreads();

  for (int t = 0; t < nt; ++t) {
    const int cur = t & 1;
    if (t + 1 < nt) stage(t + 1);

    // skip waves whose rows are entirely above this KV tile (fully masked)
    if (t * 64 <= u * 128 + wave * 32 + 31) {
      // ---- S^T = K @ Q^T : sc[tj][n], row=kpos(quad*4+r), col=qrow(l15) ----
      f32x4 sc[4][2] = {};
      __builtin_amdgcn_s_setprio(1);
#pragma unroll
      for (int ks = 0; ks < 4; ++ks)
#pragma unroll
        for (int tj = 0; tj < 4; ++tj) {
          int row = tj * 16 + l15;
          bf16x8 kf = *(const bf16x8*)(&Ks[cur][0] + row * 128
                                       + (((ks * 4 + quad) ^ (row & 15)) * 8));
          sc[tj][0] = mfma16(kf, qf[0][ks], sc[tj][0]);
          sc[tj][1] = mfma16(kf, qf[1][ks], sc[tj][1]);
        }
      __builtin_amdgcn_s_setprio(0);

      // ---- online softmax (defer-max, THR=8) ----
      const bool diag = (t >= 2 * u);
      const int kbase = t * 64 - u * 128;
#pragma unroll
      for (int n = 0; n < 2; ++n) {
        int qloc = wave * 32 + n * 16 + l15;
        if (diag) {
#pragma unroll
          for (int tj = 0; tj < 4; ++tj)
#pragma unroll
            for (int r = 0; r < 4; ++r)
              if (kbase + tj * 16 + quad * 4 + r > qloc) sc[tj][n][r] = NEG_INF;
        }
        float m = NEG_INF;
#pragma unroll
        for (int tj = 0; tj < 4; ++tj)
#pragma unroll
          for (int r = 0; r < 4; ++r) m = fmaxf(m, sc[tj][n][r]);
        m = fmaxf(m, __shfl_xor(m, 16));
        m = fmaxf(m, __shfl_xor(m, 32));
        if (!__all(m - m_run[n] <= 8.0f)) {
          float mnew = fmaxf(m_run[n], m);
          float alpha = __expf(m_run[n] - mnew);
          m_run[n] = mnew;
          l_run[n] *= alpha;
#pragma unroll
          for (int tj = 0; tj < 8; ++tj) oacc[tj][n] *= alpha;
        }
        float rs = 0.f;
#pragma unroll
        for (int tj = 0; tj < 4; ++tj)
#pragma unroll
          for (int r = 0; r < 4; ++r) {
            float p = __expf(sc[tj][n][r] - m_run[n]);
            sc[tj][n][r] = p;
            rs += p;
          }
        rs += __shfl_xor(rs, 16);
        rs += __shfl_xor(rs, 32);
        l_run[n] += rs;
      }

      // ---- P^T -> per-wave LDS (b64 writes), read back as B frags (b128) ----
      u16* pw = &Pts[wave][0];
      bf16x8 pf0[2], pf1[2];
#pragma unroll
      for (int tj = 0; tj < 4; ++tj) {
        union { u32 w[2]; uint2 u2; } pk;
        pk.w[0] = pack2bf(sc[tj][0][0], sc[tj][0][1]);
        pk.w[1] = pack2bf(sc[tj][0][2], sc[tj][0][3]);
        *(uint2*)(pw + l15 * 64 + (((tj * 4 + quad) ^ swz) * 4)) = pk.u2;
      }
      __asm__ volatile("s_waitcnt lgkmcnt(0)" ::: "memory");
#pragma unroll
      for (int ks = 0; ks < 2; ++ks)
        pf0[ks] = *(const bf16x8*)(pw + l15 * 64 + (((ks * 8 + quad * 2) ^ swz) * 4));
      __asm__ volatile("s_waitcnt lgkmcnt(0)" ::: "memory");
#pragma unroll
      for (int tj = 0; tj < 4; ++tj) {
        union { u32 w[2]; uint2 u2; } pk;
        pk.w[0] = pack2bf(sc[tj][1][0], sc[tj][1][1]);
        pk.w[1] = pack2bf(sc[tj][1][2], sc[tj][1][3]);
        *(uint2*)(pw + l15 * 64 + (((tj * 4 + quad) ^ swz) * 4)) = pk.u2;
      }
      __asm__ volatile("s_waitcnt lgkmcnt(0)" ::: "memory");
#pragma unroll
      for (int ks = 0; ks < 2; ++ks)
        pf1[ks] = *(const bf16x8*)(pw + l15 * 64 + (((ks * 8 + quad * 2) ^ swz) * 4));

      // ---- O^T += V^T @ P^T ----
      __builtin_amdgcn_s_setprio(1);
#pragma unroll
      for (int ks = 0; ks < 2; ++ks)
#pragma unroll
        for (int tj = 0; tj < 8; ++tj) {
          int row = tj * 16 + l15;
          bf16x8 vf = *(const bf16x8*)(&Vs[cur][0] + row * 64
                                       + (((ks * 4 + quad) ^ (row & 7)) * 8));
          oacc[tj][0] = mfma16(vf, pf0[ks], oacc[tj][0]);
          oacc[tj][1] = mfma16(vf, pf1[ks], oacc[tj][1]);
        }
      __builtin_amdgcn_s_setprio(0);
    }

    __syncthreads();   // vmcnt(0): stage(t+1) landed; publishes to all waves
  }

  // ---- epilogue: O^T tile row=d(quad*4+r), col=qrow(l15); pack 4 bf16 ----
#pragma unroll
  for (int n = 0; n < 2; ++n) {
    float inv_l = 1.0f / l_run[n];
    long grow = u * 128 + wave * 32 + n * 16 + l15;
#pragma unroll
    for (int tj = 0; tj < 8; ++tj) {
      int gcol = h * HD + tj * 16 + quad * 4;
      union { u32 w[2]; uint2 u2; } pk;
      pk.w[0] = pack2bf(oacc[tj][n][0] * inv_l, oacc[tj][n][1] * inv_l);
      pk.w[1] = pack2bf(oacc[tj][n][2] * inv_l, oacc[tj][n][3] * inv_l);
      *(uint2*)(Ob + grow * (HQ * HD) + gcol) = pk.u2;
    }
  }
}

// ---------- host ----------
#define MB (1024L * 1024L)

extern "C" void kernel_launch(void* const* d_in, const int* in_sizes, int n_in,
                              void* d_out, int out_size, void* d_ws, size_t ws_size,
                              hipStream_t stream) {
  const float* x    = (const float*)d_in[0];
  const float* fcos = (const float*)d_in[1];
  const float* fsin = (const float*)d_in[2];
  const float* wq   = (const float*)d_in[3];
  const float* wk   = (const float*)d_in[4];
  const float* wv   = (const float*)d_in[5];
  const float* wo   = (const float*)d_in[6];
  float* out = (float*)d_out;

  char* ws = (char*)d_ws;
  u16* wt    = (u16*)(ws + 0 * MB);     // 48 MB: QKV weights^T (6144,4096); reused for wo^T
  u16* xb    = (u16*)(ws + 48 * MB);    // 16 MB
  u16* QKVb  = (u16*)(ws + 64 * MB);    // 24 MB: (S, 6144) bf16
  u16* Qb    = (u16*)(ws + 88 * MB);    // 16 MB
  u16* Kb    = (u16*)(ws + 104 * MB);   // 4 MB
  u16* Vt    = (u16*)(ws + 108 * MB);   // 4 MB
  u16* attnb = (u16*)(ws + 112 * MB);   // 16 MB

  const int M = S_LEN, D = D_MODEL;

  // x -> bf16
  cvt_f32_bf16<<<(M * D) / 1024, 256, 0, stream>>>(x, xb, M * D);

  // weights^T (concat rows: wq^T | wk^T | wv^T), 64x64-tile transpose
  transpose_f32_bf16<<<dim3(D / 64, D / 64), dim3(64, 4), 0, stream>>>(wq, wt, D, HQ * HD);
  transpose_f32_bf16<<<dim3((HK * HD) / 64, D / 64), dim3(64, 4), 0, stream>>>(
      wk, wt + (long)(HQ * HD) * D, D, HK * HD);
  transpose_f32_bf16<<<dim3((HK * HD) / 64, D / 64), dim3(64, 4), 0, stream>>>(
      wv, wt + (long)(HQ * HD + HK * HD) * D, D, HK * HD);

  // fused QKV projection -> bf16  (gemm_pf, grid 32x8 = 256 wgs, 1 block/CU)
  gemm_pf<192, 2, true><<<dim3(NQKV / 192, M / 256), 512, 0, stream>>>(
      xb, wt, QKVb, NQKV, D);

  // RoPE (scale folded into Q) from QKV slices
  rope_bf16<<<(M * HQ * 64) / 256, 256, 0, stream>>>(
      QKVb, fcos, fsin, Qb, HQ, NQKV, 0, 0.08838834764831845f);
  rope_bf16<<<(M * HK * 64) / 256, 256, 0, stream>>>(
      QKVb, fcos, fsin, Kb, HK, NQKV, HQ * HD, 1.0f);
  // V^T from QKV slice
  transpose_bf16<<<dim3((HK * HD) / 32, M / 32), dim3(32, 8), 0, stream>>>(
      QKVb, Vt, M, HK * HD, NQKV, HQ * HD + HK * HD);

  // flash attention
  attn_fwd<<<dim3(16, HQ), 256, 0, stream>>>(Qb, Kb, Vt, attnb);

  // out = attn @ wo  (gemm_pf, grid 32x8 = 256 wgs, 1 block/CU)
  transpose_f32_bf16<<<dim3(D / 64, D / 64), dim3(64, 4), 0, stream>>>(wo, wt, HQ * HD, D);
  gemm_pf<128, 4, false><<<dim3(D / 128, M / 256), 512, 0, stream>>>(
      attnb, wt, out, D, HQ * HD);
}